// Round 24
// baseline (334.113 us; speedup 1.0000x reference)
//
#include <hip/hip_runtime.h>

#define TOK 8192
#define DMODEL 1024
#define NHEAD 16
#define SEQ 2048
#define HDIM 64
#define NQB 16

typedef __attribute__((ext_vector_type(8))) short short8;
typedef __attribute__((ext_vector_type(4))) float f32x4;

__device__ __forceinline__ ushort f2bf(float f){
  unsigned int u = __float_as_uint(f);
  u = u + 0x7fffu + ((u >> 16) & 1u);
  return (ushort)(u >> 16);
}

// packed f32x2 -> bf16x2 (low = a, high = b). No builtin on gfx950; T12 recipe.
__device__ __forceinline__ unsigned int pkbf(float a, float b){
  unsigned int r;
  asm("v_cvt_pk_bf16_f32 %0, %1, %2" : "=v"(r) : "v"(a), "v"(b));
  return r;
}

__device__ __forceinline__ void gld16(const void* g, void* l){
  __builtin_amdgcn_global_load_lds((const __attribute__((address_space(1))) unsigned int*)g,
                                   (__attribute__((address_space(3))) unsigned int*)l, 16, 0, 0);
}

__global__ __launch_bounds__(256) void cvt_kernel(const float* __restrict__ src, ushort* __restrict__ dst, int n4){
  int i = blockIdx.x * 256 + threadIdx.x;
  if(i < n4){
    float4 v = ((const float4*)src)[i];
    ushort4 o;
    o.x = f2bf(v.x); o.y = f2bf(v.y); o.z = f2bf(v.z); o.w = f2bf(v.w);
    ((ushort4*)dst)[i] = o;
  }
}

__device__ __forceinline__ float waveRedSum(float v){
  #pragma unroll
  for(int off = 32; off; off >>= 1) v += __shfl_xor(v, off);
  return v;
}

__global__ __launch_bounds__(256) void ln_kernel(const float* __restrict__ x, const float* __restrict__ g,
                                                 const float* __restrict__ bt, ushort* __restrict__ out){
  int row = blockIdx.x, t = threadIdx.x;
  float4 v = ((const float4*)(x + (size_t)row * DMODEL))[t];
  float s  = v.x + v.y + v.z + v.w;
  float sq = v.x*v.x + v.y*v.y + v.z*v.z + v.w*v.w;
  s = waveRedSum(s); sq = waveRedSum(sq);
  __shared__ float ss[4], ssq[4];
  if((t & 63) == 0){ ss[t >> 6] = s; ssq[t >> 6] = sq; }
  __syncthreads();
  float S  = ss[0] + ss[1] + ss[2] + ss[3];
  float SQ = ssq[0] + ssq[1] + ssq[2] + ssq[3];
  float mean = S * (1.f / DMODEL);
  float var  = SQ * (1.f / DMODEL) - mean * mean;
  float rstd = rsqrtf(var + 1e-5f);
  float4 gv = ((const float4*)g)[t];
  float4 bv = ((const float4*)bt)[t];
  ushort4 o;
  o.x = f2bf((v.x - mean) * rstd * gv.x + bv.x);
  o.y = f2bf((v.y - mean) * rstd * gv.y + bv.y);
  o.z = f2bf((v.z - mean) * rstd * gv.z + bv.z);
  o.w = f2bf((v.w - mean) * rstd * gv.w + bv.w);
  ((ushort4*)(out + (size_t)row * DMODEL))[t] = o;
}

// grid: (TOK/64, NHEAD), 256 threads. q,k row-major [B,H,S,64]; v transposed [B,H,64,S].
__global__ __launch_bounds__(256) void qkv_kernel(const ushort* __restrict__ h, const ushort* __restrict__ wqkv,
                                                  const float* __restrict__ bq, const float* __restrict__ bk,
                                                  const float* __restrict__ bv,
                                                  ushort* __restrict__ q, ushort* __restrict__ k, ushort* __restrict__ vT){
  __shared__ __attribute__((aligned(16))) ushort hs[64 * 72];
  __shared__ __attribute__((aligned(16))) ushort wsh[3][64 * 72];
  int head = blockIdx.y;
  int tb = blockIdx.x * 64;
  int t = threadIdx.x;
  int r = t >> 2, c0 = (t & 3) * 16;
  {
    const uint4* src = (const uint4*)(h + (size_t)(tb + r) * DMODEL + head * 64 + c0);
    uint4 p0 = src[0], p1 = src[1];
    *(uint4*)&hs[r * 72 + c0] = p0;
    *(uint4*)&hs[r * 72 + c0 + 8] = p1;
  }
  #pragma unroll
  for(int o = 0; o < 3; o++){
    const uint4* wsrc = (const uint4*)(wqkv + ((size_t)(o * NHEAD + head) * 64 + r) * 64 + c0);
    uint4 a0 = wsrc[0], a1 = wsrc[1];
    *(uint4*)&wsh[o][r * 72 + c0] = a0;
    *(uint4*)&wsh[o][r * 72 + c0 + 8] = a1;
  }
  __syncthreads();
  int w = t >> 6, l = t & 63, lr = l & 15, lg = l >> 4;
  short8 a0 = *(const short8*)&hs[(w * 16 + lr) * 72 + lg * 8];
  short8 a1 = *(const short8*)&hs[(w * 16 + lr) * 72 + 32 + lg * 8];
  const float* biases[3] = {bq, bk, bv};
  ushort* outs[2] = {q, k};
  #pragma unroll
  for(int o = 0; o < 3; o++){
    #pragma unroll
    for(int nt = 0; nt < 4; nt++){
      f32x4 acc = {0.f, 0.f, 0.f, 0.f};
      short8 b0 = *(const short8*)&wsh[o][(nt * 16 + lr) * 72 + lg * 8];
      short8 b1 = *(const short8*)&wsh[o][(nt * 16 + lr) * 72 + 32 + lg * 8];
      acc = __builtin_amdgcn_mfma_f32_16x16x32_bf16(a0, b0, acc, 0, 0, 0);
      acc = __builtin_amdgcn_mfma_f32_16x16x32_bf16(a1, b1, acc, 0, 0, 0);
      float bias = biases[o][head * 64 + nt * 16 + lr];
      #pragma unroll
      for(int rr = 0; rr < 4; rr++){
        int tok = tb + w * 16 + lg * 4 + rr;
        int b_ = tok >> 11, s_ = tok & (SEQ - 1);
        if(o < 2){
          outs[o][((size_t)(b_ * NHEAD + head) * SEQ + s_) * 64 + nt * 16 + lr] = f2bf(acc[rr] + bias);
        } else {
          vT[((size_t)(b_ * NHEAD + head) * 64 + nt * 16 + lr) * SEQ + s_] = f2bf(acc[rr] + bias);
        }
      }
    }
  }
}

// grid: (16, 64) = 1024 blocks, 256 threads (4 waves, 32 q-rows each). One 128-row q-block per
// block; longest first. Swapped QK^T in-register softmax; P->bf16 via v_cvt_pk_bf16_f32.
__global__ __launch_bounds__(256) void attn_kernel(const ushort* __restrict__ q, const ushort* __restrict__ k,
                                                   const ushort* __restrict__ vT, ushort* __restrict__ attn){
  __shared__ __attribute__((aligned(16))) ushort kt[2][64 * 64];
  __shared__ __attribute__((aligned(16))) ushort vt[2][64 * 64];
  __shared__ __attribute__((aligned(16))) ushort pt[4 * 32 * 72];
  int lid = blockIdx.y * 16 + blockIdx.x;
  int qb = (NQB - 1) - (lid >> 6);
  int bh = lid & 63;
  int t = threadIdx.x, w = t >> 6, l = t & 63, lr = l & 15, lg = l >> 4;
  size_t base = (size_t)bh * SEQ * 64;
  int b_ = bh >> 4, head = bh & 15;

  int r8 = l >> 3, c8 = l & 7;
  int st_row = 8 * w + r8;
  int st_sc  = ((c8 ^ r8) << 3);
  int st_dst = w * 1024 + l * 16;
  int xm  = (lr & 7) << 3;
  int cb0 = (lg * 8) ^ xm;
  int cb1 = (32 + lg * 8) ^ xm;

  const float C = 0.18033688f;             // 0.125 * log2(e)

  int cur = 0;
  int qbase = qb * 128;
  int wrow = qbase + w * 32;

  short8 qf[2][2];
  #pragma unroll
  for(int mt = 0; mt < 2; mt++)
    #pragma unroll
    for(int kc = 0; kc < 2; kc++)
      qf[mt][kc] = *(const short8*)&q[base + (size_t)(wrow + mt * 16 + lr) * 64 + kc * 32 + lg * 8];

  f32x4 acc_o[2][4];
  #pragma unroll
  for(int i = 0; i < 2; i++)
    #pragma unroll
    for(int jj = 0; jj < 4; jj++) acc_o[i][jj] = (f32x4){0.f, 0.f, 0.f, 0.f};
  float m_sw[2] = {-__builtin_inff(), -__builtin_inff()};
  float l_sw[2] = {0.f, 0.f};

  int jmax = (qbase + 128) >> 6;
  {
    const ushort* kp = k + base + (size_t)st_row * 64 + st_sc;
    char* kd = (char*)&kt[cur][0] + st_dst;
    gld16(kp, kd);
    gld16(kp + 32 * 64, kd + 4096);
    const ushort* vp = vT + base + (size_t)st_row * SEQ + st_sc;
    char* vd = (char*)&vt[cur][0] + st_dst;
    gld16(vp, vd);
    gld16(vp + 32 * SEQ, vd + 4096);
  }
  #pragma unroll 1
  for(int j = 0; j < jmax; j++){
    __syncthreads();
    if(j + 1 < jmax){
      int kb2 = (j + 1) * 64;
      const ushort* kp = k + base + (size_t)(kb2 + st_row) * 64 + st_sc;
      char* kd = (char*)&kt[cur ^ 1][0] + st_dst;
      gld16(kp, kd);
      gld16(kp + 32 * 64, kd + 4096);
      const ushort* vp = vT + base + (size_t)st_row * SEQ + kb2 + st_sc;
      char* vd = (char*)&vt[cur ^ 1][0] + st_dst;
      gld16(vp, vd);
      gld16(vp + 32 * SEQ, vd + 4096);
    }
    int kb = j * 64;
    if(kb <= wrow + 31){
      f32x4 sacc[2][4];
      #pragma unroll
      for(int nt = 0; nt < 4; nt++){
        short8 b0 = *(const short8*)&kt[cur][(nt * 16 + lr) * 64 + cb0];
        short8 b1 = *(const short8*)&kt[cur][(nt * 16 + lr) * 64 + cb1];
        #pragma unroll
        for(int mt = 0; mt < 2; mt++){
          f32x4 z = (f32x4){0.f, 0.f, 0.f, 0.f};
          z = __builtin_amdgcn_mfma_f32_16x16x32_bf16(b0, qf[mt][0], z, 0, 0, 0);
          z = __builtin_amdgcn_mfma_f32_16x16x32_bf16(b1, qf[mt][1], z, 0, 0, 0);
          sacc[mt][nt] = z;
        }
      }
      if(kb + 63 > wrow){
        #pragma unroll
        for(int mt = 0; mt < 2; mt++)
          #pragma unroll
          for(int nt = 0; nt < 4; nt++)
            #pragma unroll
            for(int rr = 0; rr < 4; rr++){
              int kcol = kb + nt * 16 + lg * 4 + rr;
              int qrow = wrow + mt * 16 + lr;
              if(kcol > qrow) sacc[mt][nt][rr] = -__builtin_inff();
            }
      }
      #pragma unroll
      for(int mt = 0; mt < 2; mt++){
        float tm = sacc[mt][0][0];
        #pragma unroll
        for(int nt = 0; nt < 4; nt++)
          #pragma unroll
          for(int rr = 0; rr < 4; rr++) tm = fmaxf(tm, sacc[mt][nt][rr]);
        tm = fmaxf(tm, __shfl_xor(tm, 16));
        tm = fmaxf(tm, __shfl_xor(tm, 32));
        float nm = fmaxf(m_sw[mt], tm);
        if(__any((nm - m_sw[mt]) > 44.0f)){
          float sc = exp2f((m_sw[mt] - nm) * C);
          l_sw[mt] *= sc;
          m_sw[mt] = nm;
          #pragma unroll
          for(int rr = 0; rr < 4; rr++){
            float scb = __shfl(sc, lg * 4 + rr, 16);
            #pragma unroll
            for(int nt = 0; nt < 4; nt++) acc_o[mt][nt][rr] *= scb;
          }
        }
        float mC = m_sw[mt] * C;
        float rs = 0.f;
        #pragma unroll
        for(int nt = 0; nt < 4; nt++){
          float p0 = exp2f(fmaf(sacc[mt][nt][0], C, -mC));
          float p1 = exp2f(fmaf(sacc[mt][nt][1], C, -mC));
          float p2 = exp2f(fmaf(sacc[mt][nt][2], C, -mC));
          float p3 = exp2f(fmaf(sacc[mt][nt][3], C, -mC));
          rs += (p0 + p1) + (p2 + p3);
          uint2 pw;
          pw.x = pkbf(p0, p1);
          pw.y = pkbf(p2, p3);
          *(uint2*)&pt[w * 2304 + (mt * 16 + lr) * 72 + nt * 16 + lg * 4] = pw;
        }
        rs += __shfl_xor(rs, 16);
        rs += __shfl_xor(rs, 32);
        l_sw[mt] += rs;
      }
      #pragma unroll
      for(int kc = 0; kc < 2; kc++){
        short8 pf[2];
        #pragma unroll
        for(int mt = 0; mt < 2; mt++)
          pf[mt] = *(const short8*)&pt[w * 2304 + (mt * 16 + lr) * 72 + kc * 32 + lg * 8];
        int cb = kc ? cb1 : cb0;
        #pragma unroll
        for(int nt = 0; nt < 4; nt++){
          short8 vb = *(const short8*)&vt[cur][(nt * 16 + lr) * 64 + cb];
          #pragma unroll
          for(int mt = 0; mt < 2; mt++)
            acc_o[mt][nt] = __builtin_amdgcn_mfma_f32_16x16x32_bf16(pf[mt], vb, acc_o[mt][nt], 0, 0, 0);
        }
      }
    }
    cur ^= 1;
  }
  #pragma unroll
  for(int mt = 0; mt < 2; mt++){
    float inv = 1.f / l_sw[mt];
    #pragma unroll
    for(int rr = 0; rr < 4; rr++){
      float invb = __shfl(inv, lg * 4 + rr, 16);
      #pragma unroll
      for(int nt = 0; nt < 4; nt++){
        int s_ = wrow + mt * 16 + lg * 4 + rr;
        attn[((size_t)(b_ * SEQ + s_)) * DMODEL + head * 64 + nt * 16 + lr] = f2bf(acc_o[mt][nt][rr] * invb);
      }
    }
  }
}

// tanh-form GELU: ~9 VALU vs ~25-30 for erff; |dev| from exact ~3e-4 << bf16 quantum.
__device__ __forceinline__ float gelu_fast(float x){
  float u = x * x;
  float v = fmaf(0.044715f, u, 1.0f);
  float y = 2.3021178f * x * v;
  float e = exp2f(y);
  float r = __builtin_amdgcn_rcpf(e + 1.0f);
  return x - x * r;
}

// Ring-2 BK=64 GEMM — now the best structure for ALL the big GEMMs (r23: proj+ffn2 -19.5us).
// Per K-iter {8 gld16 prefetch, gate vmcnt(8)/0, barrier, 16 ds_read_b128, 32 MFMA (setprio),
// lgkmcnt(0), barrier} — 2x MFMA per barrier-pair vs BK=32. Work-per-barrier beat residency
// head-to-head: ffn2 BK=64@2blk (~88us) < ffn1 BK=32@4blk (~100us), identical FLOPs.
// 128B rows: swizzle granule g' = g ^ (row&7); source pre-swizzle ((t&7)^((t>>3)&7))<<3,
// read ((kc*4+lg)^(R&7))<<3 — same involution both sides (rule #21). Ring-2 WAR ledger as
// r18; gate precedes publish barrier (r7 cross-wave rule). LDS 64KB, launch_bounds(256,2).
// C[m,n] = sum_k A[m,k]*W[n,k]. EPI 0: outf = acc+bias+res ; EPI 1: outb = bf16(gelu(acc+bias))
template<int EPI>
__global__ __launch_bounds__(256, 2) void gemmk64(const ushort* __restrict__ A, const ushort* __restrict__ W,
                                                  const float* __restrict__ bias, const float* __restrict__ res,
                                                  float* __restrict__ outf, ushort* __restrict__ outb,
                                                  int M, int N, int K){
  __shared__ __attribute__((aligned(16))) ushort As[2][128 * 64];
  __shared__ __attribute__((aligned(16))) ushort Bs[2][128 * 64];
  int t = threadIdx.x;
  int nwg = gridDim.x * gridDim.y;
  int id = blockIdx.y * gridDim.x + blockIdx.x;
  int bx = blockIdx.x, by = blockIdx.y;
  if((nwg & 7) == 0){
    int qq = nwg >> 3;
    int sw = (id & 7) * qq + (id >> 3);
    bx = sw % gridDim.x; by = sw / gridDim.x;
  }
  int n0 = bx * 128, m0 = by * 128;
  int w = t >> 6, l = t & 63, lr = l & 15, lg = l >> 4;
  int wm = w >> 1, wn = w & 1;

  f32x4 acc[4][4];
  #pragma unroll
  for(int i = 0; i < 4; i++)
    #pragma unroll
    for(int j = 0; j < 4; j++) acc[i][j] = (f32x4){0.f, 0.f, 0.f, 0.f};

  int ktiles = K >> 6;
  int srow = t >> 3;                                  // 0..31
  int ssc = (((t & 7) ^ ((t >> 3) & 7)) << 3);        // pre-swizzled source col (elems)

  auto stage = [&](int tile){
    int b = tile & 1;
    int k0 = tile << 6;
    char* ad = (char*)&As[b][0] + t * 16;
    char* bd = (char*)&Bs[b][0] + t * 16;
    #pragma unroll
    for(int i = 0; i < 4; i++){
      gld16(A + (size_t)(m0 + i * 32 + srow) * K + k0 + ssc, ad + i * 4096);
      gld16(W + (size_t)(n0 + i * 32 + srow) * K + k0 + ssc, bd + i * 4096);
    }
  };

  stage(0);

  int arow = wm * 64, brow = wn * 64;

  #pragma unroll 1
  for(int kt = 0; kt < ktiles; kt++){
    int b = kt & 1;
    if(kt + 1 < ktiles) stage(kt + 1);
    __builtin_amdgcn_sched_barrier(0);
    if(kt + 1 < ktiles) asm volatile("s_waitcnt vmcnt(8)" ::: "memory");
    else                asm volatile("s_waitcnt vmcnt(0)" ::: "memory");
    __builtin_amdgcn_sched_barrier(0);
    __builtin_amdgcn_s_barrier();

    short8 af[4][2], bf[4][2];
    #pragma unroll
    for(int mf = 0; mf < 4; mf++){
      int R = arow + mf * 16 + lr;
      #pragma unroll
      for(int kc = 0; kc < 2; kc++)
        af[mf][kc] = *(const short8*)&As[b][R * 64 + (((kc * 4 + lg) ^ (R & 7)) << 3)];
    }
    #pragma unroll
    for(int nf = 0; nf < 4; nf++){
      int R = brow + nf * 16 + lr;
      #pragma unroll
      for(int kc = 0; kc < 2; kc++)
        bf[nf][kc] = *(const short8*)&Bs[b][R * 64 + (((kc * 4 + lg) ^ (R & 7)) << 3)];
    }

    __builtin_amdgcn_s_setprio(1);
    #pragma unroll
    for(int mf = 0; mf < 4; mf++)
      #pragma unroll
      for(int nf = 0; nf < 4; nf++){
        acc[mf][nf] = __builtin_amdgcn_mfma_f32_16x16x32_bf16(af[mf][0], bf[nf][0], acc[mf][nf], 0, 0, 0);
        acc[mf][nf] = __builtin_amdgcn_mfma_f32_16x16x32_bf16(af[mf][1], bf[nf][1], acc[mf][nf], 0, 0, 0);
      }
    __builtin_amdgcn_s_setprio(0);

    asm volatile("s_waitcnt lgkmcnt(0)" ::: "memory");
    __builtin_amdgcn_sched_barrier(0);
    __builtin_amdgcn_s_barrier();
  }

  #pragma unroll
  for(int mf = 0; mf < 4; mf++)
    #pragma unroll
    for(int nf = 0; nf < 4; nf++){
      int col = n0 + wn * 64 + nf * 16 + lr;
      float bv = bias[col];
      #pragma unroll
      for(int rr = 0; rr < 4; rr++){
        int row = m0 + wm * 64 + mf * 16 + lg * 4 + rr;
        float val = acc[mf][nf][rr] + bv;
        if(EPI == 0){
          outf[(size_t)row * N + col] = val + res[(size_t)row * N + col];
        } else {
          outb[(size_t)row * N + col] = f2bf(gelu_fast(val));
        }
      }
    }
}

extern "C" void kernel_launch(void* const* d_in, const int* in_sizes, int n_in,
                              void* d_out, int out_size, void* d_ws, size_t ws_size,
                              hipStream_t stream){
  const float* x   = (const float*)d_in[0];
  const float* g1  = (const float*)d_in[1];
  const float* be1 = (const float*)d_in[2];
  const float* Wq  = (const float*)d_in[3];
  const float* bq  = (const float*)d_in[4];
  const float* Wk  = (const float*)d_in[5];
  const float* bk  = (const float*)d_in[6];
  const float* Wv  = (const float*)d_in[7];
  const float* bv  = (const float*)d_in[8];
  const float* Wp  = (const float*)d_in[9];
  const float* bp  = (const float*)d_in[10];
  const float* g2  = (const float*)d_in[11];
  const float* be2 = (const float*)d_in[12];
  const float* W1  = (const float*)d_in[13];
  const float* b1  = (const float*)d_in[14];
  const float* W2  = (const float*)d_in[15];
  const float* b2  = (const float*)d_in[16];
  float* out = (float*)d_out;
  char* ws = (char*)d_ws;

  ushort* wqkv = (ushort*)(ws + 0);
  ushort* wp   = (ushort*)(ws + 393216);
  ushort* w1   = (ushort*)(ws + 2490368);
  ushort* w2   = (ushort*)(ws + 10878976);
  ushort* hbuf = (ushort*)(ws + 19267584);
  ushort* qbuf = (ushort*)(ws + 36044800);
  ushort* kbuf = (ushort*)(ws + 52822016);
  ushort* vTbuf= (ushort*)(ws + 69599232);
  ushort* ff1  = (ushort*)(ws + 86376448);
  ushort* attnb = hbuf;
  ushort* h2 = qbuf;

  cvt_kernel<<<64, 256, 0, stream>>>(Wq, wqkv, 16384);
  cvt_kernel<<<64, 256, 0, stream>>>(Wk, wqkv + 65536, 16384);
  cvt_kernel<<<64, 256, 0, stream>>>(Wv, wqkv + 131072, 16384);
  cvt_kernel<<<1024, 256, 0, stream>>>(Wp, wp, 262144);
  cvt_kernel<<<4096, 256, 0, stream>>>(W1, w1, 1048576);
  cvt_kernel<<<4096, 256, 0, stream>>>(W2, w2, 1048576);

  ln_kernel<<<TOK, 256, 0, stream>>>(x, g1, be1, hbuf);
  qkv_kernel<<<dim3(TOK / 64, NHEAD), 256, 0, stream>>>(hbuf, wqkv, bq, bk, bv, qbuf, kbuf, vTbuf);
  attn_kernel<<<dim3(16, 64), 256, 0, stream>>>(qbuf, kbuf, vTbuf, attnb);
  gemmk64<0><<<dim3(8, 64), 256, 0, stream>>>(attnb, wp, bp, x, out, nullptr, 8192, 1024, 1024);
  ln_kernel<<<TOK, 256, 0, stream>>>(out, g2, be2, h2);
  if(ws_size >= 153485312ull){
    gemmk64<1><<<dim3(32, 64), 256, 0, stream>>>(h2, w1, b1, nullptr, nullptr, ff1, 8192, 4096, 1024);
    gemmk64<0><<<dim3(8, 64), 256, 0, stream>>>(ff1, w2, b2, out, out, nullptr, 8192, 1024, 4096);
  } else {
    for(int c = 0; c < 4; c++){
      gemmk64<1><<<dim3(32, 16), 256, 0, stream>>>(h2 + (size_t)c * 2048 * 1024, w1, b1, nullptr, nullptr, ff1,
                                                   2048, 4096, 1024);
      gemmk64<0><<<dim3(8, 16), 256, 0, stream>>>(ff1, w2, b2, out + (size_t)c * 2048 * 1024,
                                                  out + (size_t)c * 2048 * 1024, nullptr, 2048, 1024, 4096);
    }
  }
}

// Round 25
// 329.754 us; speedup vs baseline: 1.0132x; 1.0132x over previous
//
#include <hip/hip_runtime.h>

#define TOK 8192
#define DMODEL 1024
#define NHEAD 16
#define SEQ 2048
#define HDIM 64
#define NQB 16

typedef __attribute__((ext_vector_type(8))) short short8;
typedef __attribute__((ext_vector_type(4))) float f32x4;

__device__ __forceinline__ ushort f2bf(float f){
  unsigned int u = __float_as_uint(f);
  u = u + 0x7fffu + ((u >> 16) & 1u);
  return (ushort)(u >> 16);
}

// packed f32x2 -> bf16x2 (low = a, high = b). No builtin on gfx950; T12 recipe.
__device__ __forceinline__ unsigned int pkbf(float a, float b){
  unsigned int r;
  asm("v_cvt_pk_bf16_f32 %0, %1, %2" : "=v"(r) : "v"(a), "v"(b));
  return r;
}

__device__ __forceinline__ void gld16(const void* g, void* l){
  __builtin_amdgcn_global_load_lds((const __attribute__((address_space(1))) unsigned int*)g,
                                   (__attribute__((address_space(3))) unsigned int*)l, 16, 0, 0);
}

__global__ __launch_bounds__(256) void cvt_kernel(const float* __restrict__ src, ushort* __restrict__ dst, int n4){
  int i = blockIdx.x * 256 + threadIdx.x;
  if(i < n4){
    float4 v = ((const float4*)src)[i];
    ushort4 o;
    o.x = f2bf(v.x); o.y = f2bf(v.y); o.z = f2bf(v.z); o.w = f2bf(v.w);
    ((ushort4*)dst)[i] = o;
  }
}

__device__ __forceinline__ float waveRedSum(float v){
  #pragma unroll
  for(int off = 32; off; off >>= 1) v += __shfl_xor(v, off);
  return v;
}

__global__ __launch_bounds__(256) void ln_kernel(const float* __restrict__ x, const float* __restrict__ g,
                                                 const float* __restrict__ bt, ushort* __restrict__ out){
  int row = blockIdx.x, t = threadIdx.x;
  float4 v = ((const float4*)(x + (size_t)row * DMODEL))[t];
  float s  = v.x + v.y + v.z + v.w;
  float sq = v.x*v.x + v.y*v.y + v.z*v.z + v.w*v.w;
  s = waveRedSum(s); sq = waveRedSum(sq);
  __shared__ float ss[4], ssq[4];
  if((t & 63) == 0){ ss[t >> 6] = s; ssq[t >> 6] = sq; }
  __syncthreads();
  float S  = ss[0] + ss[1] + ss[2] + ss[3];
  float SQ = ssq[0] + ssq[1] + ssq[2] + ssq[3];
  float mean = S * (1.f / DMODEL);
  float var  = SQ * (1.f / DMODEL) - mean * mean;
  float rstd = rsqrtf(var + 1e-5f);
  float4 gv = ((const float4*)g)[t];
  float4 bv = ((const float4*)bt)[t];
  ushort4 o;
  o.x = f2bf((v.x - mean) * rstd * gv.x + bv.x);
  o.y = f2bf((v.y - mean) * rstd * gv.y + bv.y);
  o.z = f2bf((v.z - mean) * rstd * gv.z + bv.z);
  o.w = f2bf((v.w - mean) * rstd * gv.w + bv.w);
  ((ushort4*)(out + (size_t)row * DMODEL))[t] = o;
}

// grid: (TOK/64, NHEAD), 256 threads. q,k row-major [B,H,S,64]; v transposed [B,H,64,S].
__global__ __launch_bounds__(256) void qkv_kernel(const ushort* __restrict__ h, const ushort* __restrict__ wqkv,
                                                  const float* __restrict__ bq, const float* __restrict__ bk,
                                                  const float* __restrict__ bv,
                                                  ushort* __restrict__ q, ushort* __restrict__ k, ushort* __restrict__ vT){
  __shared__ __attribute__((aligned(16))) ushort hs[64 * 72];
  __shared__ __attribute__((aligned(16))) ushort wsh[3][64 * 72];
  int head = blockIdx.y;
  int tb = blockIdx.x * 64;
  int t = threadIdx.x;
  int r = t >> 2, c0 = (t & 3) * 16;
  {
    const uint4* src = (const uint4*)(h + (size_t)(tb + r) * DMODEL + head * 64 + c0);
    uint4 p0 = src[0], p1 = src[1];
    *(uint4*)&hs[r * 72 + c0] = p0;
    *(uint4*)&hs[r * 72 + c0 + 8] = p1;
  }
  #pragma unroll
  for(int o = 0; o < 3; o++){
    const uint4* wsrc = (const uint4*)(wqkv + ((size_t)(o * NHEAD + head) * 64 + r) * 64 + c0);
    uint4 a0 = wsrc[0], a1 = wsrc[1];
    *(uint4*)&wsh[o][r * 72 + c0] = a0;
    *(uint4*)&wsh[o][r * 72 + c0 + 8] = a1;
  }
  __syncthreads();
  int w = t >> 6, l = t & 63, lr = l & 15, lg = l >> 4;
  short8 a0 = *(const short8*)&hs[(w * 16 + lr) * 72 + lg * 8];
  short8 a1 = *(const short8*)&hs[(w * 16 + lr) * 72 + 32 + lg * 8];
  const float* biases[3] = {bq, bk, bv};
  ushort* outs[2] = {q, k};
  #pragma unroll
  for(int o = 0; o < 3; o++){
    #pragma unroll
    for(int nt = 0; nt < 4; nt++){
      f32x4 acc = {0.f, 0.f, 0.f, 0.f};
      short8 b0 = *(const short8*)&wsh[o][(nt * 16 + lr) * 72 + lg * 8];
      short8 b1 = *(const short8*)&wsh[o][(nt * 16 + lr) * 72 + 32 + lg * 8];
      acc = __builtin_amdgcn_mfma_f32_16x16x32_bf16(a0, b0, acc, 0, 0, 0);
      acc = __builtin_amdgcn_mfma_f32_16x16x32_bf16(a1, b1, acc, 0, 0, 0);
      float bias = biases[o][head * 64 + nt * 16 + lr];
      #pragma unroll
      for(int rr = 0; rr < 4; rr++){
        int tok = tb + w * 16 + lg * 4 + rr;
        int b_ = tok >> 11, s_ = tok & (SEQ - 1);
        if(o < 2){
          outs[o][((size_t)(b_ * NHEAD + head) * SEQ + s_) * 64 + nt * 16 + lr] = f2bf(acc[rr] + bias);
        } else {
          vT[((size_t)(b_ * NHEAD + head) * 64 + nt * 16 + lr) * SEQ + s_] = f2bf(acc[rr] + bias);
        }
      }
    }
  }
}

// grid: (16, 64) = 1024 blocks, 256 threads (4 waves, 32 q-rows each). One 128-row q-block per
// block; longest first. Swapped QK^T in-register softmax; P->bf16 via v_cvt_pk_bf16_f32.
__global__ __launch_bounds__(256) void attn_kernel(const ushort* __restrict__ q, const ushort* __restrict__ k,
                                                   const ushort* __restrict__ vT, ushort* __restrict__ attn){
  __shared__ __attribute__((aligned(16))) ushort kt[2][64 * 64];
  __shared__ __attribute__((aligned(16))) ushort vt[2][64 * 64];
  __shared__ __attribute__((aligned(16))) ushort pt[4 * 32 * 72];
  int lid = blockIdx.y * 16 + blockIdx.x;
  int qb = (NQB - 1) - (lid >> 6);
  int bh = lid & 63;
  int t = threadIdx.x, w = t >> 6, l = t & 63, lr = l & 15, lg = l >> 4;
  size_t base = (size_t)bh * SEQ * 64;
  int b_ = bh >> 4, head = bh & 15;

  int r8 = l >> 3, c8 = l & 7;
  int st_row = 8 * w + r8;
  int st_sc  = ((c8 ^ r8) << 3);
  int st_dst = w * 1024 + l * 16;
  int xm  = (lr & 7) << 3;
  int cb0 = (lg * 8) ^ xm;
  int cb1 = (32 + lg * 8) ^ xm;

  const float C = 0.18033688f;             // 0.125 * log2(e)

  int cur = 0;
  int qbase = qb * 128;
  int wrow = qbase + w * 32;

  short8 qf[2][2];
  #pragma unroll
  for(int mt = 0; mt < 2; mt++)
    #pragma unroll
    for(int kc = 0; kc < 2; kc++)
      qf[mt][kc] = *(const short8*)&q[base + (size_t)(wrow + mt * 16 + lr) * 64 + kc * 32 + lg * 8];

  f32x4 acc_o[2][4];
  #pragma unroll
  for(int i = 0; i < 2; i++)
    #pragma unroll
    for(int jj = 0; jj < 4; jj++) acc_o[i][jj] = (f32x4){0.f, 0.f, 0.f, 0.f};
  float m_sw[2] = {-__builtin_inff(), -__builtin_inff()};
  float l_sw[2] = {0.f, 0.f};

  int jmax = (qbase + 128) >> 6;
  {
    const ushort* kp = k + base + (size_t)st_row * 64 + st_sc;
    char* kd = (char*)&kt[cur][0] + st_dst;
    gld16(kp, kd);
    gld16(kp + 32 * 64, kd + 4096);
    const ushort* vp = vT + base + (size_t)st_row * SEQ + st_sc;
    char* vd = (char*)&vt[cur][0] + st_dst;
    gld16(vp, vd);
    gld16(vp + 32 * SEQ, vd + 4096);
  }
  #pragma unroll 1
  for(int j = 0; j < jmax; j++){
    __syncthreads();
    if(j + 1 < jmax){
      int kb2 = (j + 1) * 64;
      const ushort* kp = k + base + (size_t)(kb2 + st_row) * 64 + st_sc;
      char* kd = (char*)&kt[cur ^ 1][0] + st_dst;
      gld16(kp, kd);
      gld16(kp + 32 * 64, kd + 4096);
      const ushort* vp = vT + base + (size_t)st_row * SEQ + kb2 + st_sc;
      char* vd = (char*)&vt[cur ^ 1][0] + st_dst;
      gld16(vp, vd);
      gld16(vp + 32 * SEQ, vd + 4096);
    }
    int kb = j * 64;
    if(kb <= wrow + 31){
      f32x4 sacc[2][4];
      #pragma unroll
      for(int nt = 0; nt < 4; nt++){
        short8 b0 = *(const short8*)&kt[cur][(nt * 16 + lr) * 64 + cb0];
        short8 b1 = *(const short8*)&kt[cur][(nt * 16 + lr) * 64 + cb1];
        #pragma unroll
        for(int mt = 0; mt < 2; mt++){
          f32x4 z = (f32x4){0.f, 0.f, 0.f, 0.f};
          z = __builtin_amdgcn_mfma_f32_16x16x32_bf16(b0, qf[mt][0], z, 0, 0, 0);
          z = __builtin_amdgcn_mfma_f32_16x16x32_bf16(b1, qf[mt][1], z, 0, 0, 0);
          sacc[mt][nt] = z;
        }
      }
      if(kb + 63 > wrow){
        #pragma unroll
        for(int mt = 0; mt < 2; mt++)
          #pragma unroll
          for(int nt = 0; nt < 4; nt++)
            #pragma unroll
            for(int rr = 0; rr < 4; rr++){
              int kcol = kb + nt * 16 + lg * 4 + rr;
              int qrow = wrow + mt * 16 + lr;
              if(kcol > qrow) sacc[mt][nt][rr] = -__builtin_inff();
            }
      }
      #pragma unroll
      for(int mt = 0; mt < 2; mt++){
        float tm = sacc[mt][0][0];
        #pragma unroll
        for(int nt = 0; nt < 4; nt++)
          #pragma unroll
          for(int rr = 0; rr < 4; rr++) tm = fmaxf(tm, sacc[mt][nt][rr]);
        tm = fmaxf(tm, __shfl_xor(tm, 16));
        tm = fmaxf(tm, __shfl_xor(tm, 32));
        float nm = fmaxf(m_sw[mt], tm);
        if(__any((nm - m_sw[mt]) > 44.0f)){
          float sc = exp2f((m_sw[mt] - nm) * C);
          l_sw[mt] *= sc;
          m_sw[mt] = nm;
          #pragma unroll
          for(int rr = 0; rr < 4; rr++){
            float scb = __shfl(sc, lg * 4 + rr, 16);
            #pragma unroll
            for(int nt = 0; nt < 4; nt++) acc_o[mt][nt][rr] *= scb;
          }
        }
        float mC = m_sw[mt] * C;
        float rs = 0.f;
        #pragma unroll
        for(int nt = 0; nt < 4; nt++){
          float p0 = exp2f(fmaf(sacc[mt][nt][0], C, -mC));
          float p1 = exp2f(fmaf(sacc[mt][nt][1], C, -mC));
          float p2 = exp2f(fmaf(sacc[mt][nt][2], C, -mC));
          float p3 = exp2f(fmaf(sacc[mt][nt][3], C, -mC));
          rs += (p0 + p1) + (p2 + p3);
          uint2 pw;
          pw.x = pkbf(p0, p1);
          pw.y = pkbf(p2, p3);
          *(uint2*)&pt[w * 2304 + (mt * 16 + lr) * 72 + nt * 16 + lg * 4] = pw;
        }
        rs += __shfl_xor(rs, 16);
        rs += __shfl_xor(rs, 32);
        l_sw[mt] += rs;
      }
      #pragma unroll
      for(int kc = 0; kc < 2; kc++){
        short8 pf[2];
        #pragma unroll
        for(int mt = 0; mt < 2; mt++)
          pf[mt] = *(const short8*)&pt[w * 2304 + (mt * 16 + lr) * 72 + kc * 32 + lg * 8];
        int cb = kc ? cb1 : cb0;
        #pragma unroll
        for(int nt = 0; nt < 4; nt++){
          short8 vb = *(const short8*)&vt[cur][(nt * 16 + lr) * 64 + cb];
          #pragma unroll
          for(int mt = 0; mt < 2; mt++)
            acc_o[mt][nt] = __builtin_amdgcn_mfma_f32_16x16x32_bf16(pf[mt], vb, acc_o[mt][nt], 0, 0, 0);
        }
      }
    }
    cur ^= 1;
  }
  #pragma unroll
  for(int mt = 0; mt < 2; mt++){
    float inv = 1.f / l_sw[mt];
    #pragma unroll
    for(int rr = 0; rr < 4; rr++){
      float invb = __shfl(inv, lg * 4 + rr, 16);
      #pragma unroll
      for(int nt = 0; nt < 4; nt++){
        int s_ = wrow + mt * 16 + lg * 4 + rr;
        attn[((size_t)(b_ * SEQ + s_)) * DMODEL + head * 64 + nt * 16 + lr] = f2bf(acc_o[mt][nt][rr] * invb);
      }
    }
  }
}

// tanh-form GELU: ~9 VALU vs ~25-30 for erff; |dev| from exact ~3e-4 << bf16 quantum.
__device__ __forceinline__ float gelu_fast(float x){
  float u = x * x;
  float v = fmaf(0.044715f, u, 1.0f);
  float y = 2.3021178f * x * v;
  float e = exp2f(y);
  float r = __builtin_amdgcn_rcpf(e + 1.0f);
  return x - x * r;
}

// Ring-2 BK=32 GEMM @ 4 blocks/CU — best for the LARGE-grid ffn1 (2048 blocks).
// r24 A/B closed the question: ffn1 BK=32@4blk == BK=64@2blk (~100us each), but the
// r23 split (ffn1 here, proj/ffn2 on gemmk64) measured best overall (330.4 vs 334.1).
template<int EPI>
__global__ __launch_bounds__(256, 4) void gemmsm(const ushort* __restrict__ A, const ushort* __restrict__ W,
                                                 const float* __restrict__ bias, const float* __restrict__ res,
                                                 float* __restrict__ outf, ushort* __restrict__ outb,
                                                 int M, int N, int K){
  __shared__ __attribute__((aligned(16))) ushort As[2][128 * 32];
  __shared__ __attribute__((aligned(16))) ushort Bs[2][128 * 32];
  int t = threadIdx.x;
  int nwg = gridDim.x * gridDim.y;
  int id = blockIdx.y * gridDim.x + blockIdx.x;
  int bx = blockIdx.x, by = blockIdx.y;
  if((nwg & 7) == 0){
    int qq = nwg >> 3;
    int sw = (id & 7) * qq + (id >> 3);
    bx = sw % gridDim.x; by = sw / gridDim.x;
  }
  int n0 = bx * 128, m0 = by * 128;
  int w = t >> 6, l = t & 63, lr = l & 15, lg = l >> 4;
  int wm = w >> 1, wn = w & 1;

  f32x4 acc[4][4];
  #pragma unroll
  for(int i = 0; i < 4; i++)
    #pragma unroll
    for(int j = 0; j < 4; j++) acc[i][j] = (f32x4){0.f, 0.f, 0.f, 0.f};

  int ktiles = K >> 5;
  int srow = t >> 2;
  int ssc = (((t & 3) ^ ((srow >> 1) & 3)) << 3);   // pre-swizzled source col (elems)

  auto stage = [&](int tile){
    int b = tile & 1;
    int k0 = tile << 5;
    const ushort* Ap = A + (size_t)(m0 + srow) * K + k0 + ssc;
    const ushort* Bp = W + (size_t)(n0 + srow) * K + k0 + ssc;
    char* ad = (char*)&As[b][0] + t * 16;
    char* bd = (char*)&Bs[b][0] + t * 16;
    gld16(Ap, ad);
    gld16(Ap + (size_t)64 * K, ad + 4096);
    gld16(Bp, bd);
    gld16(Bp + (size_t)64 * K, bd + 4096);
  };

  stage(0);

  int arow = wm * 64, brow = wn * 64;

  #pragma unroll 1
  for(int kt = 0; kt < ktiles; kt++){
    int b = kt & 1;
    if(kt + 1 < ktiles) stage(kt + 1);
    __builtin_amdgcn_sched_barrier(0);
    if(kt + 1 < ktiles) asm volatile("s_waitcnt vmcnt(4)" ::: "memory");
    else                asm volatile("s_waitcnt vmcnt(0)" ::: "memory");
    __builtin_amdgcn_sched_barrier(0);
    __builtin_amdgcn_s_barrier();

    short8 af[4], bf[4];
    #pragma unroll
    for(int mf = 0; mf < 4; mf++){
      int R = arow + mf * 16 + lr;
      af[mf] = *(const short8*)&As[b][R * 32 + ((lg ^ ((R >> 1) & 3)) << 3)];
    }
    #pragma unroll
    for(int nf = 0; nf < 4; nf++){
      int R = brow + nf * 16 + lr;
      bf[nf] = *(const short8*)&Bs[b][R * 32 + ((lg ^ ((R >> 1) & 3)) << 3)];
    }

    __builtin_amdgcn_s_setprio(1);
    #pragma unroll
    for(int mf = 0; mf < 4; mf++)
      #pragma unroll
      for(int nf = 0; nf < 4; nf++)
        acc[mf][nf] = __builtin_amdgcn_mfma_f32_16x16x32_bf16(af[mf], bf[nf], acc[mf][nf], 0, 0, 0);
    __builtin_amdgcn_s_setprio(0);

    asm volatile("s_waitcnt lgkmcnt(0)" ::: "memory");
    __builtin_amdgcn_sched_barrier(0);
    __builtin_amdgcn_s_barrier();
  }

  #pragma unroll
  for(int mf = 0; mf < 4; mf++)
    #pragma unroll
    for(int nf = 0; nf < 4; nf++){
      int col = n0 + wn * 64 + nf * 16 + lr;
      float bv = bias[col];
      #pragma unroll
      for(int rr = 0; rr < 4; rr++){
        int row = m0 + wm * 64 + mf * 16 + lg * 4 + rr;
        float val = acc[mf][nf][rr] + bv;
        if(EPI == 0){
          outf[(size_t)row * N + col] = val + res[(size_t)row * N + col];
        } else {
          outb[(size_t)row * N + col] = f2bf(gelu_fast(val));
        }
      }
    }
}

// Ring-2 BK=64 GEMM for GRID-CAPPED kernels (proj, ffn2: 512 blocks = 2 blk/CU regardless).
// Per K-iter {8 gld16 prefetch, gate vmcnt(8)/0, barrier, 16 ds_read_b128, 32 MFMA (setprio),
// lgkmcnt(0), barrier} — 2x MFMA per barrier-pair vs BK=32 (r23: proj+ffn2 -19.5us).
// 128B rows: swizzle granule g' = g ^ (row&7); source pre-swizzle ((t&7)^((t>>3)&7))<<3,
// read ((kc*4+lg)^(R&7))<<3 — same involution both sides (rule #21). Ring-2 WAR ledger as
// r18; gate precedes publish barrier (r7 cross-wave rule). LDS 64KB, launch_bounds(256,2).
// C[m,n] = sum_k A[m,k]*W[n,k]. EPI 0: outf = acc+bias+res ; EPI 1: outb = bf16(gelu(acc+bias))
template<int EPI>
__global__ __launch_bounds__(256, 2) void gemmk64(const ushort* __restrict__ A, const ushort* __restrict__ W,
                                                  const float* __restrict__ bias, const float* __restrict__ res,
                                                  float* __restrict__ outf, ushort* __restrict__ outb,
                                                  int M, int N, int K){
  __shared__ __attribute__((aligned(16))) ushort As[2][128 * 64];
  __shared__ __attribute__((aligned(16))) ushort Bs[2][128 * 64];
  int t = threadIdx.x;
  int nwg = gridDim.x * gridDim.y;
  int id = blockIdx.y * gridDim.x + blockIdx.x;
  int bx = blockIdx.x, by = blockIdx.y;
  if((nwg & 7) == 0){
    int qq = nwg >> 3;
    int sw = (id & 7) * qq + (id >> 3);
    bx = sw % gridDim.x; by = sw / gridDim.x;
  }
  int n0 = bx * 128, m0 = by * 128;
  int w = t >> 6, l = t & 63, lr = l & 15, lg = l >> 4;
  int wm = w >> 1, wn = w & 1;

  f32x4 acc[4][4];
  #pragma unroll
  for(int i = 0; i < 4; i++)
    #pragma unroll
    for(int j = 0; j < 4; j++) acc[i][j] = (f32x4){0.f, 0.f, 0.f, 0.f};

  int ktiles = K >> 6;
  int srow = t >> 3;                                  // 0..31
  int ssc = (((t & 7) ^ ((t >> 3) & 7)) << 3);        // pre-swizzled source col (elems)

  auto stage = [&](int tile){
    int b = tile & 1;
    int k0 = tile << 6;
    char* ad = (char*)&As[b][0] + t * 16;
    char* bd = (char*)&Bs[b][0] + t * 16;
    #pragma unroll
    for(int i = 0; i < 4; i++){
      gld16(A + (size_t)(m0 + i * 32 + srow) * K + k0 + ssc, ad + i * 4096);
      gld16(W + (size_t)(n0 + i * 32 + srow) * K + k0 + ssc, bd + i * 4096);
    }
  };

  stage(0);

  int arow = wm * 64, brow = wn * 64;

  #pragma unroll 1
  for(int kt = 0; kt < ktiles; kt++){
    int b = kt & 1;
    if(kt + 1 < ktiles) stage(kt + 1);
    __builtin_amdgcn_sched_barrier(0);
    if(kt + 1 < ktiles) asm volatile("s_waitcnt vmcnt(8)" ::: "memory");
    else                asm volatile("s_waitcnt vmcnt(0)" ::: "memory");
    __builtin_amdgcn_sched_barrier(0);
    __builtin_amdgcn_s_barrier();

    short8 af[4][2], bf[4][2];
    #pragma unroll
    for(int mf = 0; mf < 4; mf++){
      int R = arow + mf * 16 + lr;
      #pragma unroll
      for(int kc = 0; kc < 2; kc++)
        af[mf][kc] = *(const short8*)&As[b][R * 64 + (((kc * 4 + lg) ^ (R & 7)) << 3)];
    }
    #pragma unroll
    for(int nf = 0; nf < 4; nf++){
      int R = brow + nf * 16 + lr;
      #pragma unroll
      for(int kc = 0; kc < 2; kc++)
        bf[nf][kc] = *(const short8*)&Bs[b][R * 64 + (((kc * 4 + lg) ^ (R & 7)) << 3)];
    }

    __builtin_amdgcn_s_setprio(1);
    #pragma unroll
    for(int mf = 0; mf < 4; mf++)
      #pragma unroll
      for(int nf = 0; nf < 4; nf++){
        acc[mf][nf] = __builtin_amdgcn_mfma_f32_16x16x32_bf16(af[mf][0], bf[nf][0], acc[mf][nf], 0, 0, 0);
        acc[mf][nf] = __builtin_amdgcn_mfma_f32_16x16x32_bf16(af[mf][1], bf[nf][1], acc[mf][nf], 0, 0, 0);
      }
    __builtin_amdgcn_s_setprio(0);

    asm volatile("s_waitcnt lgkmcnt(0)" ::: "memory");
    __builtin_amdgcn_sched_barrier(0);
    __builtin_amdgcn_s_barrier();
  }

  #pragma unroll
  for(int mf = 0; mf < 4; mf++)
    #pragma unroll
    for(int nf = 0; nf < 4; nf++){
      int col = n0 + wn * 64 + nf * 16 + lr;
      float bv = bias[col];
      #pragma unroll
      for(int rr = 0; rr < 4; rr++){
        int row = m0 + wm * 64 + mf * 16 + lg * 4 + rr;
        float val = acc[mf][nf][rr] + bv;
        if(EPI == 0){
          outf[(size_t)row * N + col] = val + res[(size_t)row * N + col];
        } else {
          outb[(size_t)row * N + col] = f2bf(gelu_fast(val));
        }
      }
    }
}

extern "C" void kernel_launch(void* const* d_in, const int* in_sizes, int n_in,
                              void* d_out, int out_size, void* d_ws, size_t ws_size,
                              hipStream_t stream){
  const float* x   = (const float*)d_in[0];
  const float* g1  = (const float*)d_in[1];
  const float* be1 = (const float*)d_in[2];
  const float* Wq  = (const float*)d_in[3];
  const float* bq  = (const float*)d_in[4];
  const float* Wk  = (const float*)d_in[5];
  const float* bk  = (const float*)d_in[6];
  const float* Wv  = (const float*)d_in[7];
  const float* bv  = (const float*)d_in[8];
  const float* Wp  = (const float*)d_in[9];
  const float* bp  = (const float*)d_in[10];
  const float* g2  = (const float*)d_in[11];
  const float* be2 = (const float*)d_in[12];
  const float* W1  = (const float*)d_in[13];
  const float* b1  = (const float*)d_in[14];
  const float* W2  = (const float*)d_in[15];
  const float* b2  = (const float*)d_in[16];
  float* out = (float*)d_out;
  char* ws = (char*)d_ws;

  ushort* wqkv = (ushort*)(ws + 0);
  ushort* wp   = (ushort*)(ws + 393216);
  ushort* w1   = (ushort*)(ws + 2490368);
  ushort* w2   = (ushort*)(ws + 10878976);
  ushort* hbuf = (ushort*)(ws + 19267584);
  ushort* qbuf = (ushort*)(ws + 36044800);
  ushort* kbuf = (ushort*)(ws + 52822016);
  ushort* vTbuf= (ushort*)(ws + 69599232);
  ushort* ff1  = (ushort*)(ws + 86376448);
  ushort* attnb = hbuf;
  ushort* h2 = qbuf;

  cvt_kernel<<<64, 256, 0, stream>>>(Wq, wqkv, 16384);
  cvt_kernel<<<64, 256, 0, stream>>>(Wk, wqkv + 65536, 16384);
  cvt_kernel<<<64, 256, 0, stream>>>(Wv, wqkv + 131072, 16384);
  cvt_kernel<<<1024, 256, 0, stream>>>(Wp, wp, 262144);
  cvt_kernel<<<4096, 256, 0, stream>>>(W1, w1, 1048576);
  cvt_kernel<<<4096, 256, 0, stream>>>(W2, w2, 1048576);

  ln_kernel<<<TOK, 256, 0, stream>>>(x, g1, be1, hbuf);
  qkv_kernel<<<dim3(TOK / 64, NHEAD), 256, 0, stream>>>(hbuf, wqkv, bq, bk, bv, qbuf, kbuf, vTbuf);
  attn_kernel<<<dim3(16, 64), 256, 0, stream>>>(qbuf, kbuf, vTbuf, attnb);
  gemmk64<0><<<dim3(8, 64), 256, 0, stream>>>(attnb, wp, bp, x, out, nullptr, 8192, 1024, 1024);
  ln_kernel<<<TOK, 256, 0, stream>>>(out, g2, be2, h2);
  if(ws_size >= 153485312ull){
    gemmsm<1><<<dim3(32, 64), 256, 0, stream>>>(h2, w1, b1, nullptr, nullptr, ff1, 8192, 4096, 1024);
    gemmk64<0><<<dim3(8, 64), 256, 0, stream>>>(ff1, w2, b2, out, out, nullptr, 8192, 1024, 4096);
  } else {
    for(int c = 0; c < 4; c++){
      gemmsm<1><<<dim3(32, 16), 256, 0, stream>>>(h2 + (size_t)c * 2048 * 1024, w1, b1, nullptr, nullptr, ff1,
                                                  2048, 4096, 1024);
      gemmk64<0><<<dim3(8, 16), 256, 0, stream>>>(ff1, w2, b2, out + (size_t)c * 2048 * 1024,
                                                  out + (size_t)c * 2048 * 1024, nullptr, 2048, 1024, 4096);
    }
  }
}

// Round 26
// 326.835 us; speedup vs baseline: 1.0223x; 1.0089x over previous
//
#include <hip/hip_runtime.h>

#define TOK 8192
#define DMODEL 1024
#define NHEAD 16
#define SEQ 2048
#define HDIM 64
#define NQB 16

typedef __attribute__((ext_vector_type(8))) short short8;
typedef __attribute__((ext_vector_type(4))) float f32x4;

__device__ __forceinline__ ushort f2bf(float f){
  unsigned int u = __float_as_uint(f);
  u = u + 0x7fffu + ((u >> 16) & 1u);
  return (ushort)(u >> 16);
}

// packed f32x2 -> bf16x2 (low = a, high = b). No builtin on gfx950; T12 recipe.
__device__ __forceinline__ unsigned int pkbf(float a, float b){
  unsigned int r;
  asm("v_cvt_pk_bf16_f32 %0, %1, %2" : "=v"(r) : "v"(a), "v"(b));
  return r;
}

__device__ __forceinline__ void gld16(const void* g, void* l){
  __builtin_amdgcn_global_load_lds((const __attribute__((address_space(1))) unsigned int*)g,
                                   (__attribute__((address_space(3))) unsigned int*)l, 16, 0, 0);
}

__global__ __launch_bounds__(256) void cvt_kernel(const float* __restrict__ src, ushort* __restrict__ dst, int n4){
  int i = blockIdx.x * 256 + threadIdx.x;
  if(i < n4){
    float4 v = ((const float4*)src)[i];
    ushort4 o;
    o.x = f2bf(v.x); o.y = f2bf(v.y); o.z = f2bf(v.z); o.w = f2bf(v.w);
    ((ushort4*)dst)[i] = o;
  }
}

__device__ __forceinline__ float waveRedSum(float v){
  #pragma unroll
  for(int off = 32; off; off >>= 1) v += __shfl_xor(v, off);
  return v;
}

__global__ __launch_bounds__(256) void ln_kernel(const float* __restrict__ x, const float* __restrict__ g,
                                                 const float* __restrict__ bt, ushort* __restrict__ out){
  int row = blockIdx.x, t = threadIdx.x;
  float4 v = ((const float4*)(x + (size_t)row * DMODEL))[t];
  float s  = v.x + v.y + v.z + v.w;
  float sq = v.x*v.x + v.y*v.y + v.z*v.z + v.w*v.w;
  s = waveRedSum(s); sq = waveRedSum(sq);
  __shared__ float ss[4], ssq[4];
  if((t & 63) == 0){ ss[t >> 6] = s; ssq[t >> 6] = sq; }
  __syncthreads();
  float S  = ss[0] + ss[1] + ss[2] + ss[3];
  float SQ = ssq[0] + ssq[1] + ssq[2] + ssq[3];
  float mean = S * (1.f / DMODEL);
  float var  = SQ * (1.f / DMODEL) - mean * mean;
  float rstd = rsqrtf(var + 1e-5f);
  float4 gv = ((const float4*)g)[t];
  float4 bv = ((const float4*)bt)[t];
  ushort4 o;
  o.x = f2bf((v.x - mean) * rstd * gv.x + bv.x);
  o.y = f2bf((v.y - mean) * rstd * gv.y + bv.y);
  o.z = f2bf((v.z - mean) * rstd * gv.z + bv.z);
  o.w = f2bf((v.w - mean) * rstd * gv.w + bv.w);
  ((ushort4*)(out + (size_t)row * DMODEL))[t] = o;
}

// grid: (TOK/64, NHEAD), 256 threads. q,k row-major [B,H,S,64]; v transposed [B,H,64,S].
__global__ __launch_bounds__(256) void qkv_kernel(const ushort* __restrict__ h, const ushort* __restrict__ wqkv,
                                                  const float* __restrict__ bq, const float* __restrict__ bk,
                                                  const float* __restrict__ bv,
                                                  ushort* __restrict__ q, ushort* __restrict__ k, ushort* __restrict__ vT){
  __shared__ __attribute__((aligned(16))) ushort hs[64 * 72];
  __shared__ __attribute__((aligned(16))) ushort wsh[3][64 * 72];
  int head = blockIdx.y;
  int tb = blockIdx.x * 64;
  int t = threadIdx.x;
  int r = t >> 2, c0 = (t & 3) * 16;
  {
    const uint4* src = (const uint4*)(h + (size_t)(tb + r) * DMODEL + head * 64 + c0);
    uint4 p0 = src[0], p1 = src[1];
    *(uint4*)&hs[r * 72 + c0] = p0;
    *(uint4*)&hs[r * 72 + c0 + 8] = p1;
  }
  #pragma unroll
  for(int o = 0; o < 3; o++){
    const uint4* wsrc = (const uint4*)(wqkv + ((size_t)(o * NHEAD + head) * 64 + r) * 64 + c0);
    uint4 a0 = wsrc[0], a1 = wsrc[1];
    *(uint4*)&wsh[o][r * 72 + c0] = a0;
    *(uint4*)&wsh[o][r * 72 + c0 + 8] = a1;
  }
  __syncthreads();
  int w = t >> 6, l = t & 63, lr = l & 15, lg = l >> 4;
  short8 a0 = *(const short8*)&hs[(w * 16 + lr) * 72 + lg * 8];
  short8 a1 = *(const short8*)&hs[(w * 16 + lr) * 72 + 32 + lg * 8];
  const float* biases[3] = {bq, bk, bv};
  ushort* outs[2] = {q, k};
  #pragma unroll
  for(int o = 0; o < 3; o++){
    #pragma unroll
    for(int nt = 0; nt < 4; nt++){
      f32x4 acc = {0.f, 0.f, 0.f, 0.f};
      short8 b0 = *(const short8*)&wsh[o][(nt * 16 + lr) * 72 + lg * 8];
      short8 b1 = *(const short8*)&wsh[o][(nt * 16 + lr) * 72 + 32 + lg * 8];
      acc = __builtin_amdgcn_mfma_f32_16x16x32_bf16(a0, b0, acc, 0, 0, 0);
      acc = __builtin_amdgcn_mfma_f32_16x16x32_bf16(a1, b1, acc, 0, 0, 0);
      float bias = biases[o][head * 64 + nt * 16 + lr];
      #pragma unroll
      for(int rr = 0; rr < 4; rr++){
        int tok = tb + w * 16 + lg * 4 + rr;
        int b_ = tok >> 11, s_ = tok & (SEQ - 1);
        if(o < 2){
          outs[o][((size_t)(b_ * NHEAD + head) * SEQ + s_) * 64 + nt * 16 + lr] = f2bf(acc[rr] + bias);
        } else {
          vT[((size_t)(b_ * NHEAD + head) * 64 + nt * 16 + lr) * SEQ + s_] = f2bf(acc[rr] + bias);
        }
      }
    }
  }
}

// grid: (16, 64) = 1024 blocks, 256 threads (4 waves, 32 q-rows each). One 128-row q-block per
// block; longest first. Swapped QK^T in-register softmax; P->bf16 via v_cvt_pk_bf16_f32.
// Softmax denominator computed on the MATRIX pipe: acc_l = mfma(P, ones) accumulates the
// row-sum L[i]=sum_k P[i][k] (B=ones is layout-invariant), replacing 32 VALU adds + 4
// shfl_xor per tile AND the epilogue shfl redistribution (MFMA C-layout == epilogue layout).
// Max-reduce written as fmaxf triples so clang fuses to v_max3_f32 (T17).
__global__ __launch_bounds__(256) void attn_kernel(const ushort* __restrict__ q, const ushort* __restrict__ k,
                                                   const ushort* __restrict__ vT, ushort* __restrict__ attn){
  __shared__ __attribute__((aligned(16))) ushort kt[2][64 * 64];
  __shared__ __attribute__((aligned(16))) ushort vt[2][64 * 64];
  __shared__ __attribute__((aligned(16))) ushort pt[4 * 32 * 72];
  int lid = blockIdx.y * 16 + blockIdx.x;
  int qb = (NQB - 1) - (lid >> 6);
  int bh = lid & 63;
  int t = threadIdx.x, w = t >> 6, l = t & 63, lr = l & 15, lg = l >> 4;
  size_t base = (size_t)bh * SEQ * 64;
  int b_ = bh >> 4, head = bh & 15;

  int r8 = l >> 3, c8 = l & 7;
  int st_row = 8 * w + r8;
  int st_sc  = ((c8 ^ r8) << 3);
  int st_dst = w * 1024 + l * 16;
  int xm  = (lr & 7) << 3;
  int cb0 = (lg * 8) ^ xm;
  int cb1 = (32 + lg * 8) ^ xm;

  const float C = 0.18033688f;             // 0.125 * log2(e)

  short8 onesv;
  #pragma unroll
  for(int i = 0; i < 8; i++) onesv[i] = (short)0x3F80;   // bf16 1.0

  int cur = 0;
  int qbase = qb * 128;
  int wrow = qbase + w * 32;

  short8 qf[2][2];
  #pragma unroll
  for(int mt = 0; mt < 2; mt++)
    #pragma unroll
    for(int kc = 0; kc < 2; kc++)
      qf[mt][kc] = *(const short8*)&q[base + (size_t)(wrow + mt * 16 + lr) * 64 + kc * 32 + lg * 8];

  f32x4 acc_o[2][4];
  #pragma unroll
  for(int i = 0; i < 2; i++)
    #pragma unroll
    for(int jj = 0; jj < 4; jj++) acc_o[i][jj] = (f32x4){0.f, 0.f, 0.f, 0.f};
  f32x4 acc_l[2];
  acc_l[0] = (f32x4){0.f, 0.f, 0.f, 0.f};
  acc_l[1] = (f32x4){0.f, 0.f, 0.f, 0.f};
  float m_sw[2] = {-__builtin_inff(), -__builtin_inff()};

  int jmax = (qbase + 128) >> 6;
  {
    const ushort* kp = k + base + (size_t)st_row * 64 + st_sc;
    char* kd = (char*)&kt[cur][0] + st_dst;
    gld16(kp, kd);
    gld16(kp + 32 * 64, kd + 4096);
    const ushort* vp = vT + base + (size_t)st_row * SEQ + st_sc;
    char* vd = (char*)&vt[cur][0] + st_dst;
    gld16(vp, vd);
    gld16(vp + 32 * SEQ, vd + 4096);
  }
  #pragma unroll 1
  for(int j = 0; j < jmax; j++){
    __syncthreads();
    if(j + 1 < jmax){
      int kb2 = (j + 1) * 64;
      const ushort* kp = k + base + (size_t)(kb2 + st_row) * 64 + st_sc;
      char* kd = (char*)&kt[cur ^ 1][0] + st_dst;
      gld16(kp, kd);
      gld16(kp + 32 * 64, kd + 4096);
      const ushort* vp = vT + base + (size_t)st_row * SEQ + kb2 + st_sc;
      char* vd = (char*)&vt[cur ^ 1][0] + st_dst;
      gld16(vp, vd);
      gld16(vp + 32 * SEQ, vd + 4096);
    }
    int kb = j * 64;
    if(kb <= wrow + 31){
      f32x4 sacc[2][4];
      #pragma unroll
      for(int nt = 0; nt < 4; nt++){
        short8 b0 = *(const short8*)&kt[cur][(nt * 16 + lr) * 64 + cb0];
        short8 b1 = *(const short8*)&kt[cur][(nt * 16 + lr) * 64 + cb1];
        #pragma unroll
        for(int mt = 0; mt < 2; mt++){
          f32x4 z = (f32x4){0.f, 0.f, 0.f, 0.f};
          z = __builtin_amdgcn_mfma_f32_16x16x32_bf16(b0, qf[mt][0], z, 0, 0, 0);
          z = __builtin_amdgcn_mfma_f32_16x16x32_bf16(b1, qf[mt][1], z, 0, 0, 0);
          sacc[mt][nt] = z;
        }
      }
      if(kb + 63 > wrow){
        #pragma unroll
        for(int mt = 0; mt < 2; mt++)
          #pragma unroll
          for(int nt = 0; nt < 4; nt++)
            #pragma unroll
            for(int rr = 0; rr < 4; rr++){
              int kcol = kb + nt * 16 + lg * 4 + rr;
              int qrow = wrow + mt * 16 + lr;
              if(kcol > qrow) sacc[mt][nt][rr] = -__builtin_inff();
            }
      }
      #pragma unroll
      for(int mt = 0; mt < 2; mt++){
        // max-reduce as max3-fusable triples: 8 ops vs 15
        float t0 = fmaxf(fmaxf(sacc[mt][0][0], sacc[mt][0][1]), sacc[mt][0][2]);
        float t1 = fmaxf(fmaxf(sacc[mt][0][3], sacc[mt][1][0]), sacc[mt][1][1]);
        float t2 = fmaxf(fmaxf(sacc[mt][1][2], sacc[mt][1][3]), sacc[mt][2][0]);
        float t3 = fmaxf(fmaxf(sacc[mt][2][1], sacc[mt][2][2]), sacc[mt][2][3]);
        float t4 = fmaxf(fmaxf(sacc[mt][3][0], sacc[mt][3][1]), sacc[mt][3][2]);
        float u0 = fmaxf(fmaxf(t0, t1), t2);
        float u1 = fmaxf(fmaxf(t3, t4), sacc[mt][3][3]);
        float tm = fmaxf(u0, u1);
        tm = fmaxf(tm, __shfl_xor(tm, 16));
        tm = fmaxf(tm, __shfl_xor(tm, 32));
        float nm = fmaxf(m_sw[mt], tm);
        if(__any((nm - m_sw[mt]) > 44.0f)){
          float sc = exp2f((m_sw[mt] - nm) * C);
          m_sw[mt] = nm;
          #pragma unroll
          for(int rr = 0; rr < 4; rr++){
            float scb = __shfl(sc, lg * 4 + rr, 16);
            acc_l[mt][rr] *= scb;
            #pragma unroll
            for(int nt = 0; nt < 4; nt++) acc_o[mt][nt][rr] *= scb;
          }
        }
        float mC = m_sw[mt] * C;
        #pragma unroll
        for(int nt = 0; nt < 4; nt++){
          float p0 = exp2f(fmaf(sacc[mt][nt][0], C, -mC));
          float p1 = exp2f(fmaf(sacc[mt][nt][1], C, -mC));
          float p2 = exp2f(fmaf(sacc[mt][nt][2], C, -mC));
          float p3 = exp2f(fmaf(sacc[mt][nt][3], C, -mC));
          uint2 pw;
          pw.x = pkbf(p0, p1);
          pw.y = pkbf(p2, p3);
          *(uint2*)&pt[w * 2304 + (mt * 16 + lr) * 72 + nt * 16 + lg * 4] = pw;
        }
      }
      // PV + MFMA row-sum (denominator on the matrix pipe)
      #pragma unroll
      for(int kc = 0; kc < 2; kc++){
        short8 pf[2];
        #pragma unroll
        for(int mt = 0; mt < 2; mt++)
          pf[mt] = *(const short8*)&pt[w * 2304 + (mt * 16 + lr) * 72 + kc * 32 + lg * 8];
        int cb = kc ? cb1 : cb0;
        #pragma unroll
        for(int nt = 0; nt < 4; nt++){
          short8 vb = *(const short8*)&vt[cur][(nt * 16 + lr) * 64 + cb];
          #pragma unroll
          for(int mt = 0; mt < 2; mt++)
            acc_o[mt][nt] = __builtin_amdgcn_mfma_f32_16x16x32_bf16(pf[mt], vb, acc_o[mt][nt], 0, 0, 0);
        }
        #pragma unroll
        for(int mt = 0; mt < 2; mt++)
          acc_l[mt] = __builtin_amdgcn_mfma_f32_16x16x32_bf16(pf[mt], onesv, acc_l[mt], 0, 0, 0);
      }
    }
    cur ^= 1;
  }
  #pragma unroll
  for(int mt = 0; mt < 2; mt++){
    #pragma unroll
    for(int rr = 0; rr < 4; rr++){
      float invb = 1.f / acc_l[mt][rr];
      #pragma unroll
      for(int nt = 0; nt < 4; nt++){
        int s_ = wrow + mt * 16 + lg * 4 + rr;
        attn[((size_t)(b_ * SEQ + s_)) * DMODEL + head * 64 + nt * 16 + lr] = f2bf(acc_o[mt][nt][rr] * invb);
      }
    }
  }
}

// tanh-form GELU: ~9 VALU vs ~25-30 for erff; |dev| from exact ~3e-4 << bf16 quantum.
__device__ __forceinline__ float gelu_fast(float x){
  float u = x * x;
  float v = fmaf(0.044715f, u, 1.0f);
  float y = 2.3021178f * x * v;
  float e = exp2f(y);
  float r = __builtin_amdgcn_rcpf(e + 1.0f);
  return x - x * r;
}

// Ring-2 BK=32 GEMM @ 4 blocks/CU — best for the LARGE-grid ffn1 (2048 blocks).
// r24 A/B: ffn1 BK=32@4blk == BK=64@2blk (~100us), but the r23 split measured best overall.
template<int EPI>
__global__ __launch_bounds__(256, 4) void gemmsm(const ushort* __restrict__ A, const ushort* __restrict__ W,
                                                 const float* __restrict__ bias, const float* __restrict__ res,
                                                 float* __restrict__ outf, ushort* __restrict__ outb,
                                                 int M, int N, int K){
  __shared__ __attribute__((aligned(16))) ushort As[2][128 * 32];
  __shared__ __attribute__((aligned(16))) ushort Bs[2][128 * 32];
  int t = threadIdx.x;
  int nwg = gridDim.x * gridDim.y;
  int id = blockIdx.y * gridDim.x + blockIdx.x;
  int bx = blockIdx.x, by = blockIdx.y;
  if((nwg & 7) == 0){
    int qq = nwg >> 3;
    int sw = (id & 7) * qq + (id >> 3);
    bx = sw % gridDim.x; by = sw / gridDim.x;
  }
  int n0 = bx * 128, m0 = by * 128;
  int w = t >> 6, l = t & 63, lr = l & 15, lg = l >> 4;
  int wm = w >> 1, wn = w & 1;

  f32x4 acc[4][4];
  #pragma unroll
  for(int i = 0; i < 4; i++)
    #pragma unroll
    for(int j = 0; j < 4; j++) acc[i][j] = (f32x4){0.f, 0.f, 0.f, 0.f};

  int ktiles = K >> 5;
  int srow = t >> 2;
  int ssc = (((t & 3) ^ ((srow >> 1) & 3)) << 3);   // pre-swizzled source col (elems)

  auto stage = [&](int tile){
    int b = tile & 1;
    int k0 = tile << 5;
    const ushort* Ap = A + (size_t)(m0 + srow) * K + k0 + ssc;
    const ushort* Bp = W + (size_t)(n0 + srow) * K + k0 + ssc;
    char* ad = (char*)&As[b][0] + t * 16;
    char* bd = (char*)&Bs[b][0] + t * 16;
    gld16(Ap, ad);
    gld16(Ap + (size_t)64 * K, ad + 4096);
    gld16(Bp, bd);
    gld16(Bp + (size_t)64 * K, bd + 4096);
  };

  stage(0);

  int arow = wm * 64, brow = wn * 64;

  #pragma unroll 1
  for(int kt = 0; kt < ktiles; kt++){
    int b = kt & 1;
    if(kt + 1 < ktiles) stage(kt + 1);
    __builtin_amdgcn_sched_barrier(0);
    if(kt + 1 < ktiles) asm volatile("s_waitcnt vmcnt(4)" ::: "memory");
    else                asm volatile("s_waitcnt vmcnt(0)" ::: "memory");
    __builtin_amdgcn_sched_barrier(0);
    __builtin_amdgcn_s_barrier();

    short8 af[4], bf[4];
    #pragma unroll
    for(int mf = 0; mf < 4; mf++){
      int R = arow + mf * 16 + lr;
      af[mf] = *(const short8*)&As[b][R * 32 + ((lg ^ ((R >> 1) & 3)) << 3)];
    }
    #pragma unroll
    for(int nf = 0; nf < 4; nf++){
      int R = brow + nf * 16 + lr;
      bf[nf] = *(const short8*)&Bs[b][R * 32 + ((lg ^ ((R >> 1) & 3)) << 3)];
    }

    __builtin_amdgcn_s_setprio(1);
    #pragma unroll
    for(int mf = 0; mf < 4; mf++)
      #pragma unroll
      for(int nf = 0; nf < 4; nf++)
        acc[mf][nf] = __builtin_amdgcn_mfma_f32_16x16x32_bf16(af[mf], bf[nf], acc[mf][nf], 0, 0, 0);
    __builtin_amdgcn_s_setprio(0);

    asm volatile("s_waitcnt lgkmcnt(0)" ::: "memory");
    __builtin_amdgcn_sched_barrier(0);
    __builtin_amdgcn_s_barrier();
  }

  #pragma unroll
  for(int mf = 0; mf < 4; mf++)
    #pragma unroll
    for(int nf = 0; nf < 4; nf++){
      int col = n0 + wn * 64 + nf * 16 + lr;
      float bv = bias[col];
      #pragma unroll
      for(int rr = 0; rr < 4; rr++){
        int row = m0 + wm * 64 + mf * 16 + lg * 4 + rr;
        float val = acc[mf][nf][rr] + bv;
        if(EPI == 0){
          outf[(size_t)row * N + col] = val + res[(size_t)row * N + col];
        } else {
          outb[(size_t)row * N + col] = f2bf(gelu_fast(val));
        }
      }
    }
}

// Ring-2 BK=64 GEMM for GRID-CAPPED kernels (proj, ffn2: 512 blocks = 2 blk/CU regardless).
// 2x MFMA per barrier-pair vs BK=32 (r23: proj+ffn2 -19.5us). 128B rows: swizzle granule
// g' = g ^ (row&7), both-sides involution (rule #21). Ring-2 WAR ledger; gate precedes
// publish barrier (r7 cross-wave rule). LDS 64KB, launch_bounds(256,2).
template<int EPI>
__global__ __launch_bounds__(256, 2) void gemmk64(const ushort* __restrict__ A, const ushort* __restrict__ W,
                                                  const float* __restrict__ bias, const float* __restrict__ res,
                                                  float* __restrict__ outf, ushort* __restrict__ outb,
                                                  int M, int N, int K){
  __shared__ __attribute__((aligned(16))) ushort As[2][128 * 64];
  __shared__ __attribute__((aligned(16))) ushort Bs[2][128 * 64];
  int t = threadIdx.x;
  int nwg = gridDim.x * gridDim.y;
  int id = blockIdx.y * gridDim.x + blockIdx.x;
  int bx = blockIdx.x, by = blockIdx.y;
  if((nwg & 7) == 0){
    int qq = nwg >> 3;
    int sw = (id & 7) * qq + (id >> 3);
    bx = sw % gridDim.x; by = sw / gridDim.x;
  }
  int n0 = bx * 128, m0 = by * 128;
  int w = t >> 6, l = t & 63, lr = l & 15, lg = l >> 4;
  int wm = w >> 1, wn = w & 1;

  f32x4 acc[4][4];
  #pragma unroll
  for(int i = 0; i < 4; i++)
    #pragma unroll
    for(int j = 0; j < 4; j++) acc[i][j] = (f32x4){0.f, 0.f, 0.f, 0.f};

  int ktiles = K >> 6;
  int srow = t >> 3;                                  // 0..31
  int ssc = (((t & 7) ^ ((t >> 3) & 7)) << 3);        // pre-swizzled source col (elems)

  auto stage = [&](int tile){
    int b = tile & 1;
    int k0 = tile << 6;
    char* ad = (char*)&As[b][0] + t * 16;
    char* bd = (char*)&Bs[b][0] + t * 16;
    #pragma unroll
    for(int i = 0; i < 4; i++){
      gld16(A + (size_t)(m0 + i * 32 + srow) * K + k0 + ssc, ad + i * 4096);
      gld16(W + (size_t)(n0 + i * 32 + srow) * K + k0 + ssc, bd + i * 4096);
    }
  };

  stage(0);

  int arow = wm * 64, brow = wn * 64;

  #pragma unroll 1
  for(int kt = 0; kt < ktiles; kt++){
    int b = kt & 1;
    if(kt + 1 < ktiles) stage(kt + 1);
    __builtin_amdgcn_sched_barrier(0);
    if(kt + 1 < ktiles) asm volatile("s_waitcnt vmcnt(8)" ::: "memory");
    else                asm volatile("s_waitcnt vmcnt(0)" ::: "memory");
    __builtin_amdgcn_sched_barrier(0);
    __builtin_amdgcn_s_barrier();

    short8 af[4][2], bf[4][2];
    #pragma unroll
    for(int mf = 0; mf < 4; mf++){
      int R = arow + mf * 16 + lr;
      #pragma unroll
      for(int kc = 0; kc < 2; kc++)
        af[mf][kc] = *(const short8*)&As[b][R * 64 + (((kc * 4 + lg) ^ (R & 7)) << 3)];
    }
    #pragma unroll
    for(int nf = 0; nf < 4; nf++){
      int R = brow + nf * 16 + lr;
      #pragma unroll
      for(int kc = 0; kc < 2; kc++)
        bf[nf][kc] = *(const short8*)&Bs[b][R * 64 + (((kc * 4 + lg) ^ (R & 7)) << 3)];
    }

    __builtin_amdgcn_s_setprio(1);
    #pragma unroll
    for(int mf = 0; mf < 4; mf++)
      #pragma unroll
      for(int nf = 0; nf < 4; nf++){
        acc[mf][nf] = __builtin_amdgcn_mfma_f32_16x16x32_bf16(af[mf][0], bf[nf][0], acc[mf][nf], 0, 0, 0);
        acc[mf][nf] = __builtin_amdgcn_mfma_f32_16x16x32_bf16(af[mf][1], bf[nf][1], acc[mf][nf], 0, 0, 0);
      }
    __builtin_amdgcn_s_setprio(0);

    asm volatile("s_waitcnt lgkmcnt(0)" ::: "memory");
    __builtin_amdgcn_sched_barrier(0);
    __builtin_amdgcn_s_barrier();
  }

  #pragma unroll
  for(int mf = 0; mf < 4; mf++)
    #pragma unroll
    for(int nf = 0; nf < 4; nf++){
      int col = n0 + wn * 64 + nf * 16 + lr;
      float bv = bias[col];
      #pragma unroll
      for(int rr = 0; rr < 4; rr++){
        int row = m0 + wm * 64 + mf * 16 + lg * 4 + rr;
        float val = acc[mf][nf][rr] + bv;
        if(EPI == 0){
          outf[(size_t)row * N + col] = val + res[(size_t)row * N + col];
        } else {
          outb[(size_t)row * N + col] = f2bf(gelu_fast(val));
        }
      }
    }
}

extern "C" void kernel_launch(void* const* d_in, const int* in_sizes, int n_in,
                              void* d_out, int out_size, void* d_ws, size_t ws_size,
                              hipStream_t stream){
  const float* x   = (const float*)d_in[0];
  const float* g1  = (const float*)d_in[1];
  const float* be1 = (const float*)d_in[2];
  const float* Wq  = (const float*)d_in[3];
  const float* bq  = (const float*)d_in[4];
  const float* Wk  = (const float*)d_in[5];
  const float* bk  = (const float*)d_in[6];
  const float* Wv  = (const float*)d_in[7];
  const float* bv  = (const float*)d_in[8];
  const float* Wp  = (const float*)d_in[9];
  const float* bp  = (const float*)d_in[10];
  const float* g2  = (const float*)d_in[11];
  const float* be2 = (const float*)d_in[12];
  const float* W1  = (const float*)d_in[13];
  const float* b1  = (const float*)d_in[14];
  const float* W2  = (const float*)d_in[15];
  const float* b2  = (const float*)d_in[16];
  float* out = (float*)d_out;
  char* ws = (char*)d_ws;

  ushort* wqkv = (ushort*)(ws + 0);
  ushort* wp   = (ushort*)(ws + 393216);
  ushort* w1   = (ushort*)(ws + 2490368);
  ushort* w2   = (ushort*)(ws + 10878976);
  ushort* hbuf = (ushort*)(ws + 19267584);
  ushort* qbuf = (ushort*)(ws + 36044800);
  ushort* kbuf = (ushort*)(ws + 52822016);
  ushort* vTbuf= (ushort*)(ws + 69599232);
  ushort* ff1  = (ushort*)(ws + 86376448);
  ushort* attnb = hbuf;
  ushort* h2 = qbuf;

  cvt_kernel<<<64, 256, 0, stream>>>(Wq, wqkv, 16384);
  cvt_kernel<<<64, 256, 0, stream>>>(Wk, wqkv + 65536, 16384);
  cvt_kernel<<<64, 256, 0, stream>>>(Wv, wqkv + 131072, 16384);
  cvt_kernel<<<1024, 256, 0, stream>>>(Wp, wp, 262144);
  cvt_kernel<<<4096, 256, 0, stream>>>(W1, w1, 1048576);
  cvt_kernel<<<4096, 256, 0, stream>>>(W2, w2, 1048576);

  ln_kernel<<<TOK, 256, 0, stream>>>(x, g1, be1, hbuf);
  qkv_kernel<<<dim3(TOK / 64, NHEAD), 256, 0, stream>>>(hbuf, wqkv, bq, bk, bv, qbuf, kbuf, vTbuf);
  attn_kernel<<<dim3(16, 64), 256, 0, stream>>>(qbuf, kbuf, vTbuf, attnb);
  gemmk64<0><<<dim3(8, 64), 256, 0, stream>>>(attnb, wp, bp, x, out, nullptr, 8192, 1024, 1024);
  ln_kernel<<<TOK, 256, 0, stream>>>(out, g2, be2, h2);
  if(ws_size >= 153485312ull){
    gemmsm<1><<<dim3(32, 64), 256, 0, stream>>>(h2, w1, b1, nullptr, nullptr, ff1, 8192, 4096, 1024);
    gemmk64<0><<<dim3(8, 64), 256, 0, stream>>>(ff1, w2, b2, out, out, nullptr, 8192, 1024, 4096);
  } else {
    for(int c = 0; c < 4; c++){
      gemmsm<1><<<dim3(32, 16), 256, 0, stream>>>(h2 + (size_t)c * 2048 * 1024, w1, b1, nullptr, nullptr, ff1,
                                                  2048, 4096, 1024);
      gemmk64<0><<<dim3(8, 16), 256, 0, stream>>>(ff1, w2, b2, out + (size_t)c * 2048 * 1024,
                                                  out + (size_t)c * 2048 * 1024, nullptr, 2048, 1024, 4096);
    }
  }
}